// Round 3
// baseline (106.037 us; speedup 1.0000x reference)
//
#include <hip/hip_runtime.h>
#include <math.h>

// Problem constants (B=2, D=512, K=32, H=W=64 -> N=4096)
#define B_DIM 2
#define D_DIM 512
#define K_DIM 32
#define N_DIM 4096

// ---------------------------------------------------------------------------
// K0 prep: A[d,k] = s^2, B2[d,k] = -2 s^2 c, CK[k] = sum_d s^2 c^2;
// also zeroes Mv/nsq (replaces hipMemsetAsync). grid 64 x 256.
// ---------------------------------------------------------------------------
__global__ __launch_bounds__(256)
void k_prep(const float* __restrict__ CW, const float* __restrict__ SC,
            float* __restrict__ A, float* __restrict__ B2,
            float* __restrict__ CK, float* __restrict__ zeroes)
{
    __shared__ float ckred[8][33];
    const int tid = threadIdx.x;
    const int idx = blockIdx.x * 256 + tid;      // d*32 + k
    const int d = idx >> 5, k = idx & 31;
    float s = SC[idx];
    float c = CW[k * D_DIM + d];
    float a = s * s;
    A[idx]  = a;
    B2[idx] = -2.f * a * c;
    if (blockIdx.x == 0) {                       // block-uniform branch
        if (tid < 128) zeroes[tid] = 0.f;        // Mv (64) + nsq (64)
        const int kk = tid & 31, g = tid >> 5;
        float acc = 0.f;
        for (int dd = g * 64; dd < g * 64 + 64; ++dd) {
            float sv = SC[dd * K_DIM + kk];
            float cv = CW[kk * D_DIM + dd];
            float av = sv * sv;
            acc = fmaf(av * cv, cv, acc);
        }
        ckred[g][kk] = acc;
        __syncthreads();
        if (tid < 32) {
            float t = 0.f;
#pragma unroll
            for (int i = 0; i < 8; ++i) t += ckred[i][tid];
            CK[tid] = t;
        }
    }
}

// ---------------------------------------------------------------------------
// K1: distances + softmax Q + per-codeword mass M
// dist[b,n,k] = sum_d A[d,k]*x^2 + B2[d,k]*x   (+ CK[k] added at softmax)
// grid = 512 = B * 256 n-tiles of 16; block = 256 threads (4 waves)
// Thread (dp = tid&63, kp = tid>>6) owns d-slice {4dp..4dp+3, 256+4dp..+3}
// and k-slice [8kp, 8kp+8). A/B2 register tiles loaded straight from the
// prep tables (no prologue math, ~160 live VGPRs -> no spill risk at
// launch_bounds(256,2)). x streamed from LDS with 16-B lane stride
// (conflict-free ds_read_b128). d-sum: shfl_xor butterfly 64->16 + LDS.
// ---------------------------------------------------------------------------
__global__ __launch_bounds__(256, 2)
void k_dist_q(const float* __restrict__ X, const float* __restrict__ A,
              const float* __restrict__ B2, const float* __restrict__ CK,
              float* __restrict__ Qout, float* __restrict__ Mout)
{
    __shared__ __align__(16) float xlds[16 * 516];     // [n 16][d 512, stride 516]
    __shared__ __align__(16) float red[16 * 16 * 36];  // [n 16][i 16][k 32 +4]
    __shared__ float mloc[K_DIM];

    const int tid = threadIdx.x;
    const int b  = blockIdx.x >> 8;
    const int n0 = (blockIdx.x & 255) << 4;   // 16 n per block
    const int dp = tid & 63;
    const int kp = tid >> 6;
    const int k0 = kp << 3;

    if (tid < K_DIM) mloc[tid] = 0.f;

    // ---- stage 16 n x 512 d (transposed to [n][d]); 64-B coalesced reads ----
    const float* xsrc = X + (size_t)b * D_DIM * N_DIM + n0;
#pragma unroll
    for (int j = 0; j < 8; ++j) {
        const int d  = (tid >> 2) + (j << 6);
        const int n4 = (tid & 3) << 2;
        float4 v = *(const float4*)(xsrc + (size_t)d * N_DIM + n4);
        xlds[(n4 + 0) * 516 + d] = v.x;
        xlds[(n4 + 1) * 516 + d] = v.y;
        xlds[(n4 + 2) * 516 + d] = v.z;
        xlds[(n4 + 3) * 516 + d] = v.w;
    }

    // ---- register tables: pure float4 loads from prep output (L2-hot) ----
    float Ar[8][8], Br[8][8];
#pragma unroll
    for (int dd = 0; dd < 8; ++dd) {
        const int d = (dd < 4) ? ((dp << 2) + dd) : (256 + (dp << 2) + (dd - 4));
        float4 a0 = *(const float4*)(A  + d * K_DIM + k0);
        float4 a1 = *(const float4*)(A  + d * K_DIM + k0 + 4);
        float4 b0 = *(const float4*)(B2 + d * K_DIM + k0);
        float4 b1 = *(const float4*)(B2 + d * K_DIM + k0 + 4);
        Ar[dd][0] = a0.x; Ar[dd][1] = a0.y; Ar[dd][2] = a0.z; Ar[dd][3] = a0.w;
        Ar[dd][4] = a1.x; Ar[dd][5] = a1.y; Ar[dd][6] = a1.z; Ar[dd][7] = a1.w;
        Br[dd][0] = b0.x; Br[dd][1] = b0.y; Br[dd][2] = b0.z; Br[dd][3] = b0.w;
        Br[dd][4] = b1.x; Br[dd][5] = b1.y; Br[dd][6] = b1.z; Br[dd][7] = b1.w;
    }
    __syncthreads();

    // ---- main: 16 n, 128 FMA-pairs each ----
#pragma unroll
    for (int n = 0; n < 16; ++n) {
        float dist[8];
#pragma unroll
        for (int kk = 0; kk < 8; ++kk) dist[kk] = 0.f;
        float4 xa = *(const float4*)(&xlds[n * 516 + (dp << 2)]);
        float4 xb = *(const float4*)(&xlds[n * 516 + (dp << 2) + 256]);
        float xv[8] = {xa.x, xa.y, xa.z, xa.w, xb.x, xb.y, xb.z, xb.w};
#pragma unroll
        for (int dd = 0; dd < 8; ++dd) {
            const float x  = xv[dd];
            const float x2 = x * x;
#pragma unroll
            for (int kk = 0; kk < 8; ++kk) {
                dist[kk] = fmaf(Ar[dd][kk], x2, dist[kk]);
                dist[kk] = fmaf(Br[dd][kk], x,  dist[kk]);
            }
        }
#pragma unroll
        for (int kk = 0; kk < 8; ++kk) {
            dist[kk] += __shfl_xor(dist[kk], 32);
            dist[kk] += __shfl_xor(dist[kk], 16);
        }
        if (dp < 16) {
            float* r = &red[(n * 16 + dp) * 36 + k0];
            *(float4*)(r)     = make_float4(dist[0], dist[1], dist[2], dist[3]);
            *(float4*)(r + 4) = make_float4(dist[4], dist[5], dist[6], dist[7]);
        }
    }
    __syncthreads();

    // ---- reduce 16 partials + CK + softmax over k (32-lane groups) ----
#pragma unroll
    for (int h = 0; h < 2; ++h) {
        const int n = (tid >> 5) + (h << 3);
        const int k = tid & 31;
        float dsum = CK[k];
#pragma unroll
        for (int i = 0; i < 16; ++i) dsum += red[(n * 16 + i) * 36 + k];
        float m = dsum;
#pragma unroll
        for (int mk = 16; mk >= 1; mk >>= 1)
            m = fminf(m, __shfl_xor(m, mk));
        float e = __expf(-0.5f * (dsum - m));
        float ssum = e;
#pragma unroll
        for (int mk = 16; mk >= 1; mk >>= 1)
            ssum += __shfl_xor(ssum, mk);
        float q = __fdividef(e, ssum);
        Qout[((size_t)b * N_DIM + n0 + n) * K_DIM + k] = q;
        atomicAdd(&mloc[k], q);
    }
    __syncthreads();
    if (tid < K_DIM) atomicAdd(&Mout[b * K_DIM + tid], mloc[tid]);
}

// ---------------------------------------------------------------------------
// K3: T partials. T[b,d,k] = sum_n Q[b,n,k] * X[b,d,n], n split 32 ways.
// grid = 512 = b(2) x dtile(8 of 64 d) x ns(32 of 128 n); 2 blocks/CU.
// ---------------------------------------------------------------------------
__global__ __launch_bounds__(256, 2)
void k_tpart(const float* __restrict__ X, const float* __restrict__ Qin,
             float* __restrict__ TP)
{
    __shared__ __align__(16) float Xs[64 * 68];        // [d 64][n 64 +4]
    __shared__ __align__(16) float Qs[32 * 68];        // [k 32][n 64 +4]
    __shared__ __align__(16) float red4[4 * 64 * 36];  // [wave][d 64][k 32 +4]

    const int tid = threadIdx.x;
    const int bid = blockIdx.x;
    const int ns = bid & 31;
    const int dt = (bid >> 5) & 7;
    const int b  = bid >> 8;
    const int nsub = tid >> 5;
    const int dp = tid & 7;
    const int kp = (tid >> 3) & 3;
    const int wv = tid >> 6;

    float acc[8][8];
#pragma unroll
    for (int i = 0; i < 8; ++i)
#pragma unroll
        for (int j = 0; j < 8; ++j) acc[i][j] = 0.f;

    const float* xsrc = X + ((size_t)b * D_DIM + dt * 64) * N_DIM + ns * 128;
    const float* qsrc = Qin + ((size_t)b * N_DIM + ns * 128) * K_DIM;

    for (int ch = 0; ch < 2; ++ch) {   // 2 chunks of 64 n
        __syncthreads();
#pragma unroll
        for (int i = 0; i < 4; ++i) {  // stage Xs: 64 d x 64 n
            int flat4 = tid + (i << 8);
            int row = flat4 >> 4;
            int c4  = (flat4 & 15) << 2;
            float4 v = *(const float4*)(xsrc + (size_t)row * N_DIM + (ch << 6) + c4);
            *(float4*)(&Xs[row * 68 + c4]) = v;
        }
#pragma unroll
        for (int i = 0; i < 2; ++i) {  // stage Qs transposed: [k][n]
            int flat4 = tid + (i << 8);
            int nn = flat4 >> 3;
            int k4 = (flat4 & 7) << 2;
            float4 v = *(const float4*)(qsrc + ((ch << 6) + nn) * K_DIM + k4);
            Qs[(k4 + 0) * 68 + nn] = v.x;
            Qs[(k4 + 1) * 68 + nn] = v.y;
            Qs[(k4 + 2) * 68 + nn] = v.z;
            Qs[(k4 + 3) * 68 + nn] = v.w;
        }
        __syncthreads();
#pragma unroll
        for (int s = 0; s < 2; ++s) {
            const int nb = (nsub << 3) + (s << 2);
            float4 xr[8], qr[8];
#pragma unroll
            for (int i = 0; i < 8; ++i)
                xr[i] = *(const float4*)(&Xs[(dp + (i << 3)) * 68 + nb]);
#pragma unroll
            for (int j = 0; j < 8; ++j)
                qr[j] = *(const float4*)(&Qs[(kp + (j << 2)) * 68 + nb]);
#pragma unroll
            for (int i = 0; i < 8; ++i)
#pragma unroll
                for (int j = 0; j < 8; ++j) {
                    acc[i][j] = fmaf(xr[i].x, qr[j].x, acc[i][j]);
                    acc[i][j] = fmaf(xr[i].y, qr[j].y, acc[i][j]);
                    acc[i][j] = fmaf(xr[i].z, qr[j].z, acc[i][j]);
                    acc[i][j] = fmaf(xr[i].w, qr[j].w, acc[i][j]);
                }
        }
    }
    // pair-reduce nsub (2w, 2w+1) via shfl, then per-wave slabs (no atomics)
    __syncthreads();
#pragma unroll
    for (int i = 0; i < 8; ++i)
#pragma unroll
        for (int j = 0; j < 8; ++j)
            acc[i][j] += __shfl_xor(acc[i][j], 32);
    if ((tid & 32) == 0) {
#pragma unroll
        for (int i = 0; i < 8; ++i)
#pragma unroll
            for (int j = 0; j < 8; ++j)
                red4[(wv * 64 + dp + (i << 3)) * 36 + kp + (j << 2)] = acc[i][j];
    }
    __syncthreads();
    // sum 4 wave slabs, store 64x32 tile (coalesced)
    float* dst = TP + (((size_t)ns * 2 + b) * D_DIM + dt * 64) * K_DIM;
#pragma unroll
    for (int e = 0; e < 8; ++e) {
        int flat = tid + (e << 8);          // 2048 cells
        int dl = flat >> 5;
        int k  = flat & 31;
        float s = red4[(0 * 64 + dl) * 36 + k] + red4[(1 * 64 + dl) * 36 + k]
                + red4[(2 * 64 + dl) * 36 + k] + red4[(3 * 64 + dl) * 36 + k];
        dst[dl * K_DIM + k] = s;
    }
}

// ---------------------------------------------------------------------------
// K4a: sum 32 partials, Z_ = s*(T/M - c); write Ztmp; accumulate sum_d Z_^2
// grid 128 = b(2) x 64 d-slices of 8
// ---------------------------------------------------------------------------
__global__ __launch_bounds__(256)
void k_zpre(const float* __restrict__ TP, const float* __restrict__ Mv,
            const float* __restrict__ CW, const float* __restrict__ SC,
            float* __restrict__ Ztmp, float* __restrict__ nsq)
{
    __shared__ float part[8][33];
    const int tid = threadIdx.x;
    const int b  = blockIdx.x >> 6;
    const int ds = blockIdx.x & 63;
    const int d  = (ds << 3) + (tid >> 5);
    const int k  = tid & 31;
    float sum = 0.f;
#pragma unroll
    for (int ns = 0; ns < 32; ++ns)
        sum += TP[(((size_t)ns * 2 + b) * D_DIM + d) * K_DIM + k];
    float m = Mv[b * K_DIM + k];
    float c = CW[k * D_DIM + d];
    float s = SC[d * K_DIM + k];
    float z = s * (sum / m - c);
    Ztmp[((size_t)b * D_DIM + d) * K_DIM + k] = z;
    part[tid >> 5][k] = z * z;
    __syncthreads();
    if (tid < K_DIM) {
        float t = 0.f;
#pragma unroll
        for (int i = 0; i < 8; ++i) t += part[i][tid];
        atomicAdd(&nsq[b * K_DIM + tid], t);
    }
}

// K4c: Z = Ztmp * rsqrt(nsq)
__global__ __launch_bounds__(256)
void k_zfin(const float* __restrict__ Ztmp, const float* __restrict__ nsq,
            float* __restrict__ Z)
{
    const int tid = threadIdx.x;
    const int b  = blockIdx.x >> 6;
    const int ds = blockIdx.x & 63;
    const int d  = (ds << 3) + (tid >> 5);
    const int k  = tid & 31;
    const int idx = ((b * D_DIM) + d) * K_DIM + k;
    Z[idx] = Ztmp[idx] * rsqrtf(nsq[b * K_DIM + k]);
}

extern "C" void kernel_launch(void* const* d_in, const int* in_sizes, int n_in,
                              void* d_out, int out_size, void* d_ws, size_t ws_size,
                              hipStream_t stream)
{
    const float* X  = (const float*)d_in[0];   // [2,512,64,64]
    const float* CW = (const float*)d_in[1];   // [32,512]
    const float* SC = (const float*)d_in[2];   // [512,32]
    float* Z = (float*)d_out;                              // [2,512,32]
    float* Q = (float*)d_out + B_DIM * D_DIM * K_DIM;      // [2,4096,32]

    float* W   = (float*)d_ws;
    float* Mv  = W;                  // 64 floats
    float* nsq = W + 64;             // 64 floats
    float* TP  = W + 256;            // 32*2*512*32 = 1,048,576 floats (4 MB)
    float* ZT  = TP + 32 * B_DIM * D_DIM * K_DIM;   // 32768 floats
    float* At  = ZT + B_DIM * D_DIM * K_DIM;        // 16384 floats
    float* Bt  = At + D_DIM * K_DIM;                // 16384 floats
    float* CKt = Bt + D_DIM * K_DIM;                // 32 floats

    k_prep  <<< 64, 256, 0, stream>>>(CW, SC, At, Bt, CKt, W);
    k_dist_q<<<512, 256, 0, stream>>>(X, At, Bt, CKt, Q, Mv);
    k_tpart <<<512, 256, 0, stream>>>(X, Q, TP);
    k_zpre  <<<128, 256, 0, stream>>>(TP, Mv, CW, SC, ZT, nsq);
    k_zfin  <<<128, 256, 0, stream>>>(ZT, nsq, Z);
}

// Round 4
// 96.292 us; speedup vs baseline: 1.1012x; 1.1012x over previous
//
#include <hip/hip_runtime.h>
#include <math.h>

// Problem constants (B=2, D=512, K=32, H=W=64 -> N=4096)
#define B_DIM 2
#define D_DIM 512
#define K_DIM 32
#define N_DIM 4096

// ---------------------------------------------------------------------------
// K1: distances + softmax Q. Also zeroes nsq (consumed 2 dispatches later).
// dist[b,n,k] = sum_d A*x^2 + B2*x + A*c^2,  A = s^2, B2 = -2 s^2 c
// grid = 512 = B * 256 n-tiles of 16; block = 256 threads (4 waves)
// Thread (dp = tid&63, kp = tid>>6) owns d-slice {4dp..4dp+3, 256+4dp..+3}
// and k-slice [8kp, 8kp+8). A/B2 in registers; x streamed from LDS with
// 16-B lane stride (conflict-free ds_read_b128). d-sum: shfl_xor butterfly
// 64->16 + LDS + softmax. No M atomics (M comes from Mpart in k_tpart).
// ---------------------------------------------------------------------------
__global__ __launch_bounds__(256, 2)
void k_dist_q(const float* __restrict__ X, const float* __restrict__ CW,
              const float* __restrict__ SC, float* __restrict__ Qout,
              float* __restrict__ nsq)
{
    __shared__ __align__(16) float xlds[16 * 516];     // [n 16][d 512, stride 516]
    __shared__ __align__(16) float red[16 * 16 * 36];  // [n 16][i 16][k 32 +4]

    const int tid = threadIdx.x;
    const int b  = blockIdx.x >> 8;
    const int n0 = (blockIdx.x & 255) << 4;   // 16 n per block
    const int dp = tid & 63;
    const int kp = tid >> 6;
    const int k0 = kp << 3;

    if (blockIdx.x == 0 && tid < 2 * K_DIM) nsq[tid] = 0.f;

    // ---- stage 16 n x 512 d (transposed to [n][d]); 64-B coalesced reads ----
    const float* xsrc = X + (size_t)b * D_DIM * N_DIM + n0;
#pragma unroll
    for (int j = 0; j < 8; ++j) {
        const int d  = (tid >> 2) + (j << 6);
        const int n4 = (tid & 3) << 2;
        float4 v = *(const float4*)(xsrc + (size_t)d * N_DIM + n4);
        xlds[(n4 + 0) * 516 + d] = v.x;
        xlds[(n4 + 1) * 516 + d] = v.y;
        xlds[(n4 + 2) * 516 + d] = v.z;
        xlds[(n4 + 3) * 516 + d] = v.w;
    }

    // ---- prologue: register tables (overlaps other waves' staging) ----
    float cv[8][8];                    // cv[kk][dd] = codeword value
#pragma unroll
    for (int kk = 0; kk < 8; ++kk) {
        const float* cr = CW + (k0 + kk) * D_DIM + (dp << 2);
        float4 c0 = *(const float4*)(cr);
        float4 c1 = *(const float4*)(cr + 256);
        cv[kk][0] = c0.x; cv[kk][1] = c0.y; cv[kk][2] = c0.z; cv[kk][3] = c0.w;
        cv[kk][4] = c1.x; cv[kk][5] = c1.y; cv[kk][6] = c1.z; cv[kk][7] = c1.w;
    }
    float Areg[8][8], Breg[8][8], ckp[8];
#pragma unroll
    for (int kk = 0; kk < 8; ++kk) ckp[kk] = 0.f;
#pragma unroll
    for (int dd = 0; dd < 8; ++dd) {
        const int d = (dd < 4) ? ((dp << 2) + dd) : (256 + (dp << 2) + (dd - 4));
        float4 s0 = *(const float4*)(SC + d * K_DIM + k0);
        float4 s1 = *(const float4*)(SC + d * K_DIM + k0 + 4);
        float sv[8] = {s0.x, s0.y, s0.z, s0.w, s1.x, s1.y, s1.z, s1.w};
#pragma unroll
        for (int kk = 0; kk < 8; ++kk) {
            float c = cv[kk][dd];
            float a = sv[kk] * sv[kk];
            Areg[dd][kk] = a;
            Breg[dd][kk] = -2.f * a * c;
            ckp[kk] = fmaf(a * c, c, ckp[kk]);
        }
    }
    __syncthreads();

    // ---- main: 16 n, 128 FMA-pairs each ----
#pragma unroll
    for (int n = 0; n < 16; ++n) {
        float dist[8];
#pragma unroll
        for (int kk = 0; kk < 8; ++kk) dist[kk] = ckp[kk];
        float4 xa = *(const float4*)(&xlds[n * 516 + (dp << 2)]);
        float4 xb = *(const float4*)(&xlds[n * 516 + (dp << 2) + 256]);
        float xv[8] = {xa.x, xa.y, xa.z, xa.w, xb.x, xb.y, xb.z, xb.w};
#pragma unroll
        for (int dd = 0; dd < 8; ++dd) {
            const float x  = xv[dd];
            const float x2 = x * x;
#pragma unroll
            for (int kk = 0; kk < 8; ++kk) {
                dist[kk] = fmaf(Areg[dd][kk], x2, dist[kk]);
                dist[kk] = fmaf(Breg[dd][kk], x,  dist[kk]);
            }
        }
#pragma unroll
        for (int kk = 0; kk < 8; ++kk) {
            dist[kk] += __shfl_xor(dist[kk], 32);
            dist[kk] += __shfl_xor(dist[kk], 16);
        }
        if (dp < 16) {
            float* r = &red[(n * 16 + dp) * 36 + k0];
            *(float4*)(r)     = make_float4(dist[0], dist[1], dist[2], dist[3]);
            *(float4*)(r + 4) = make_float4(dist[4], dist[5], dist[6], dist[7]);
        }
    }
    __syncthreads();

    // ---- reduce 16 partials + softmax over k (32-lane groups), 2 passes ----
#pragma unroll
    for (int h = 0; h < 2; ++h) {
        const int n = (tid >> 5) + (h << 3);
        const int k = tid & 31;
        float dsum = 0.f;
#pragma unroll
        for (int i = 0; i < 16; ++i) dsum += red[(n * 16 + i) * 36 + k];
        float m = dsum;
#pragma unroll
        for (int mk = 16; mk >= 1; mk >>= 1)
            m = fminf(m, __shfl_xor(m, mk));
        float e = __expf(-0.5f * (dsum - m));
        float ssum = e;
#pragma unroll
        for (int mk = 16; mk >= 1; mk >>= 1)
            ssum += __shfl_xor(ssum, mk);
        Qout[((size_t)b * N_DIM + n0 + n) * K_DIM + k] = __fdividef(e, ssum);
    }
}

// ---------------------------------------------------------------------------
// K2: T partials + per-slab Q mass. T[b,d,k] = sum_n Q[b,n,k] * X[b,d,n],
// n split 32 ways. grid = 512 = b(2) x dtile(8 of 64 d) x ns(32 of 128 n).
// dt==0 blocks additionally write Mpart[ns,b,k] = sum_{128 n} Q (no atomics).
// ---------------------------------------------------------------------------
__global__ __launch_bounds__(256, 2)
void k_tpart(const float* __restrict__ X, const float* __restrict__ Qin,
             float* __restrict__ TP, float* __restrict__ Mpart)
{
    __shared__ __align__(16) float Xs[64 * 68];        // [d 64][n 64 +4]
    __shared__ __align__(16) float Qs[32 * 68];        // [k 32][n 64 +4]
    __shared__ __align__(16) float red4[4 * 64 * 36];  // [wave][d 64][k 32 +4]
    __shared__ float mred[8][33];

    const int tid = threadIdx.x;
    const int bid = blockIdx.x;
    const int ns = bid & 31;
    const int dt = (bid >> 5) & 7;
    const int b  = bid >> 8;
    const int nsub = tid >> 5;
    const int dp = tid & 7;
    const int kp = (tid >> 3) & 3;
    const int wv = tid >> 6;

    float acc[8][8];
#pragma unroll
    for (int i = 0; i < 8; ++i)
#pragma unroll
        for (int j = 0; j < 8; ++j) acc[i][j] = 0.f;

    const float* xsrc = X + ((size_t)b * D_DIM + dt * 64) * N_DIM + ns * 128;
    const float* qsrc = Qin + ((size_t)b * N_DIM + ns * 128) * K_DIM;

    for (int ch = 0; ch < 2; ++ch) {   // 2 chunks of 64 n
        __syncthreads();
#pragma unroll
        for (int i = 0; i < 4; ++i) {  // stage Xs: 64 d x 64 n
            int flat4 = tid + (i << 8);
            int row = flat4 >> 4;
            int c4  = (flat4 & 15) << 2;
            float4 v = *(const float4*)(xsrc + (size_t)row * N_DIM + (ch << 6) + c4);
            *(float4*)(&Xs[row * 68 + c4]) = v;
        }
#pragma unroll
        for (int i = 0; i < 2; ++i) {  // stage Qs transposed: [k][n]
            int flat4 = tid + (i << 8);
            int nn = flat4 >> 3;
            int k4 = (flat4 & 7) << 2;
            float4 v = *(const float4*)(qsrc + ((ch << 6) + nn) * K_DIM + k4);
            Qs[(k4 + 0) * 68 + nn] = v.x;
            Qs[(k4 + 1) * 68 + nn] = v.y;
            Qs[(k4 + 2) * 68 + nn] = v.z;
            Qs[(k4 + 3) * 68 + nn] = v.w;
        }
        __syncthreads();
#pragma unroll
        for (int s = 0; s < 2; ++s) {
            const int nb = (nsub << 3) + (s << 2);
            float4 xr[8], qr[8];
#pragma unroll
            for (int i = 0; i < 8; ++i)
                xr[i] = *(const float4*)(&Xs[(dp + (i << 3)) * 68 + nb]);
#pragma unroll
            for (int j = 0; j < 8; ++j)
                qr[j] = *(const float4*)(&Qs[(kp + (j << 2)) * 68 + nb]);
#pragma unroll
            for (int i = 0; i < 8; ++i)
#pragma unroll
                for (int j = 0; j < 8; ++j) {
                    acc[i][j] = fmaf(xr[i].x, qr[j].x, acc[i][j]);
                    acc[i][j] = fmaf(xr[i].y, qr[j].y, acc[i][j]);
                    acc[i][j] = fmaf(xr[i].z, qr[j].z, acc[i][j]);
                    acc[i][j] = fmaf(xr[i].w, qr[j].w, acc[i][j]);
                }
        }
    }
    // pair-reduce nsub (2w, 2w+1) via shfl, then per-wave slabs (no atomics)
    __syncthreads();
#pragma unroll
    for (int i = 0; i < 8; ++i)
#pragma unroll
        for (int j = 0; j < 8; ++j)
            acc[i][j] += __shfl_xor(acc[i][j], 32);
    if ((tid & 32) == 0) {
#pragma unroll
        for (int i = 0; i < 8; ++i)
#pragma unroll
            for (int j = 0; j < 8; ++j)
                red4[(wv * 64 + dp + (i << 3)) * 36 + kp + (j << 2)] = acc[i][j];
    }
    __syncthreads();
    // sum 4 wave slabs, store 64x32 tile (coalesced)
    float* dst = TP + (((size_t)ns * 2 + b) * D_DIM + dt * 64) * K_DIM;
#pragma unroll
    for (int e = 0; e < 8; ++e) {
        int flat = tid + (e << 8);          // 2048 cells
        int dl = flat >> 5;
        int k  = flat & 31;
        float s = red4[(0 * 64 + dl) * 36 + k] + red4[(1 * 64 + dl) * 36 + k]
                + red4[(2 * 64 + dl) * 36 + k] + red4[(3 * 64 + dl) * 36 + k];
        dst[dl * K_DIM + k] = s;
    }
    // dt==0 blocks: per-slab Q mass (L2-hot coalesced reads, no atomics)
    if (dt == 0) {
        const int k = tid & 31, g = tid >> 5;
        float qm = 0.f;
#pragma unroll
        for (int n = 0; n < 16; ++n)
            qm += qsrc[(g * 16 + n) * K_DIM + k];
        mred[g][k] = qm;
        __syncthreads();
        if (tid < K_DIM) {
            float t = 0.f;
#pragma unroll
            for (int i = 0; i < 8; ++i) t += mred[i][tid];
            Mpart[(ns * B_DIM + b) * K_DIM + tid] = t;
        }
    }
}

// ---------------------------------------------------------------------------
// K3: sum 32 partials, M from Mpart, Z_ = s*(T/M - c); write Ztmp; nsq atomics
// grid 128 = b(2) x 64 d-slices of 8
// ---------------------------------------------------------------------------
__global__ __launch_bounds__(256)
void k_zpre(const float* __restrict__ TP, const float* __restrict__ Mpart,
            const float* __restrict__ CW, const float* __restrict__ SC,
            float* __restrict__ Ztmp, float* __restrict__ nsq)
{
    __shared__ float part[8][33];
    const int tid = threadIdx.x;
    const int b  = blockIdx.x >> 6;
    const int ds = blockIdx.x & 63;
    const int d  = (ds << 3) + (tid >> 5);
    const int k  = tid & 31;
    float sum = 0.f;
#pragma unroll
    for (int ns = 0; ns < 32; ++ns)
        sum += TP[(((size_t)ns * 2 + b) * D_DIM + d) * K_DIM + k];
    float m = 0.f;
#pragma unroll
    for (int ns = 0; ns < 32; ++ns)
        m += Mpart[(ns * B_DIM + b) * K_DIM + k];
    float c = CW[k * D_DIM + d];
    float s = SC[d * K_DIM + k];
    float z = s * (sum / m - c);
    Ztmp[((size_t)b * D_DIM + d) * K_DIM + k] = z;
    part[tid >> 5][k] = z * z;
    __syncthreads();
    if (tid < K_DIM) {
        float t = 0.f;
#pragma unroll
        for (int i = 0; i < 8; ++i) t += part[i][tid];
        atomicAdd(&nsq[b * K_DIM + tid], t);
    }
}

// K4: Z = Ztmp * rsqrt(nsq)
__global__ __launch_bounds__(256)
void k_zfin(const float* __restrict__ Ztmp, const float* __restrict__ nsq,
            float* __restrict__ Z)
{
    const int tid = threadIdx.x;
    const int b  = blockIdx.x >> 6;
    const int ds = blockIdx.x & 63;
    const int d  = (ds << 3) + (tid >> 5);
    const int k  = tid & 31;
    const int idx = ((b * D_DIM) + d) * K_DIM + k;
    Z[idx] = Ztmp[idx] * rsqrtf(nsq[b * K_DIM + k]);
}

extern "C" void kernel_launch(void* const* d_in, const int* in_sizes, int n_in,
                              void* d_out, int out_size, void* d_ws, size_t ws_size,
                              hipStream_t stream)
{
    const float* X  = (const float*)d_in[0];   // [2,512,64,64]
    const float* CW = (const float*)d_in[1];   // [32,512]
    const float* SC = (const float*)d_in[2];   // [512,32]
    float* Z = (float*)d_out;                              // [2,512,32]
    float* Q = (float*)d_out + B_DIM * D_DIM * K_DIM;      // [2,4096,32]

    float* W    = (float*)d_ws;
    float* nsq  = W;                                       // 64 floats
    float* Mpart= W + 64;                                  // 32*2*32 = 2048
    float* TP   = W + 64 + 2048;                           // 4 MB
    float* ZT   = TP + 32 * B_DIM * D_DIM * K_DIM;         // 32768 floats

    k_dist_q<<<512, 256, 0, stream>>>(X, CW, SC, Q, nsq);
    k_tpart <<<512, 256, 0, stream>>>(X, Q, TP, Mpart);
    k_zpre  <<<128, 256, 0, stream>>>(TP, Mpart, CW, SC, ZT, nsq);
    k_zfin  <<<128, 256, 0, stream>>>(ZT, nsq, Z);
}